// Round 15
// baseline (148.621 us; speedup 1.0000x reference)
//
#include <hip/hip_runtime.h>
#include <float.h>

#define L_TOK 65536
#define DIM   64
#define NCODE 1024

// ---------------------------------------------------------------------------
// Kernel A: per-code ||e||^2 (fp32), sequential-k chain.
// ---------------------------------------------------------------------------
__global__ __launch_bounds__(256) void esum_kernel(const float* __restrict__ emb,
                                                   float* __restrict__ esum) {
    int n = blockIdx.x * 256 + threadIdx.x;
    if (n >= NCODE) return;
    const float* e = emb + ((size_t)n << 6);
    float s = 0.f;
#pragma unroll
    for (int k = 0; k < DIM; ++k) s = fmaf(e[k], e[k], s);
    esum[n] = s;
}

// ---------------------------------------------------------------------------
// Kernel B: argmin — NO SMEM IN THE HOT LOOP.
// Evidence: r7-r14 plateau ~140us = per-k0 lgkmcnt(0) drains (s_load
// completes out-of-order -> every wait drains the queue -> no pipelining).
// r14 also showed usable concurrent LDS < 96KB, so occupancy is exhausted.
// This round: e served from LDS via wave-uniform ds_read_b128 broadcasts
// (DS is IN-ORDER -> compiler emits counted lgkmcnt(N), k0 pipelines).
//   - r11 shape verbatim: 4 tok/lane, 512thr/8w, VGPR ~96 clean.
//   - block = 256 tokens (64KB z, r11 staging+swizzle) x 1024 codes in 16
//     stages of 64 codes (16KB e-tile/stage; wave w takes codes
//     [s*64+8w, +8)); esum copied to LDS (4KB). 84KB, 1 block/CU, grid 256.
//   - 2 waves/SIMD is enough: 32 independent fmac chains saturate the SIMD
//     from one wave; occupancy was only hiding SMEM drains (now gone).
//   - anti-LICM opaque SGPR per stage (z-reads are stage-loop-invariant;
//     r4's 2.4GB scratch catastrophe otherwise).
// Numerics bitwise-identical to r11 (absmax 0.0): same staging/swizzle,
// same sequential k=0..63 fmaf chains (e bits identical via LDS),
// d = fmaf(a,-2,zs+es), ascending per-wave code sequence, lowest-index
// cross-wave merge == np.argmin first-wins.
// ---------------------------------------------------------------------------
__global__ __launch_bounds__(512, 2) void argmin_kernel(const float* __restrict__ z,
                                                        const float* __restrict__ emb,
                                                        const float* __restrict__ esum,
                                                        float* __restrict__ idx_out) {
    __shared__ float zl[256 * 64];     // swizzled [tok][k], 64 KB (reused by merge)
    __shared__ float el[64 * 64];      // stage e-tile [code_in_stage][k], 16 KB
    __shared__ float esl[NCODE];       // esum copy, 4 KB

    const int t    = threadIdx.x;
    const int lane = t & 63;
    const int wid  = __builtin_amdgcn_readfirstlane(t >> 6);
    char* zbytes   = (char*)zl;

    // Stage z tile (r11 pattern, proven): 256 rows, each thread 8 float4.
    {
        const int tok = t >> 1;            // 0..255
        const int kk  = (t & 1) * 32;      // 0 or 32
        const int swt = (tok & 15) << 4;
        const float* src = z + ((size_t)(blockIdx.x * 256 + tok) << 6) + kk;
#pragma unroll
        for (int i = 0; i < 8; ++i) {
            float4 v = ((const float4*)src)[i];
            *(float4*)(zbytes + tok * 256 + (((kk + 4*i) * 4) ^ swt)) = v;
        }
    }
    // Stage esum (1024 floats, 512 threads x 2).
    esl[t]       = esum[t];
    esl[t + 512] = esum[t + 512];
    __syncthreads();

    const int rbA = lane * 256;            // token A = lane
    const int rbB = rbA + 64 * 256;        // token B = lane + 64
    const int rbC = rbA + 128 * 256;       // token C = lane + 128
    const int rbD = rbA + 192 * 256;       // token D = lane + 192
    const int sw  = (lane & 15) << 4;

    // ||z||^2 per token, sequential k (chunk-ascending, x,y,z,w order).
    float zsA = 0.f, zsB = 0.f, zsC = 0.f, zsD = 0.f;
#pragma unroll
    for (int k0 = 0; k0 < 64; k0 += 4) {
        float4 a = *(const float4*)(zbytes + rbA + ((k0 * 4) ^ sw));
        float4 b = *(const float4*)(zbytes + rbB + ((k0 * 4) ^ sw));
        float4 c = *(const float4*)(zbytes + rbC + ((k0 * 4) ^ sw));
        float4 d = *(const float4*)(zbytes + rbD + ((k0 * 4) ^ sw));
        zsA = fmaf(a.x, a.x, zsA); zsA = fmaf(a.y, a.y, zsA);
        zsA = fmaf(a.z, a.z, zsA); zsA = fmaf(a.w, a.w, zsA);
        zsB = fmaf(b.x, b.x, zsB); zsB = fmaf(b.y, b.y, zsB);
        zsB = fmaf(b.z, b.z, zsB); zsB = fmaf(b.w, b.w, zsB);
        zsC = fmaf(c.x, c.x, zsC); zsC = fmaf(c.y, c.y, zsC);
        zsC = fmaf(c.z, c.z, zsC); zsC = fmaf(c.w, c.w, zsC);
        zsD = fmaf(d.x, d.x, zsD); zsD = fmaf(d.y, d.y, zsD);
        zsD = fmaf(d.z, d.z, zsD); zsD = fmaf(d.w, d.w, zsD);
    }

    float bestA = FLT_MAX, bestB = FLT_MAX, bestC = FLT_MAX, bestD = FLT_MAX;
    int   biA   = 0,       biB   = 0,       biC   = 0,       biD   = 0;

    // e-staging addresses for this thread (8 codes/wave-group layout):
    // thread t stages code (t>>3) of the stage, floats [(t&7)*8, +8).
    const int   st_code = t >> 3;               // 0..63
    const int   st_k    = (t & 7) * 8;          // 0,8,..,56
    const char* ebase_w = (const char*)el + (wid * 8) * 256;   // wave-uniform

    for (int s = 0; s < 16; ++s) {
        // ---- stage e tile: issue loads early, write after barrier ----
        const float* esrc = emb + ((size_t)(s * 64 + st_code) << 6) + st_k;
        float4 ev0 = ((const float4*)esrc)[0];
        float4 ev1 = ((const float4*)esrc)[1];
        __syncthreads();                         // prior stage fully consumed
        ((float4*)((char*)el + st_code * 256 + st_k * 4))[0] = ev0;
        ((float4*)((char*)el + st_code * 256 + st_k * 4 + 16))[0] = ev1;
        __syncthreads();                         // e tile ready

        int szero = 0;
        asm volatile("" : "+s"(szero));          // blocks LICM of z reads
        const int rA = rbA + szero;
        const int rB = rbB + szero;
        const int rC = rbC + szero;
        const int rD = rbD + szero;

        const int c0 = s * 64 + wid * 8;         // wave-uniform, ascending in s
        float a0 = 0.f, a1 = 0.f, a2 = 0.f, a3 = 0.f;
        float a4 = 0.f, a5 = 0.f, a6 = 0.f, a7 = 0.f;
        float b0 = 0.f, b1 = 0.f, b2 = 0.f, b3 = 0.f;
        float b4 = 0.f, b5 = 0.f, b6 = 0.f, b7 = 0.f;
        float c0a = 0.f, c1a = 0.f, c2a = 0.f, c3a = 0.f;
        float c4a = 0.f, c5a = 0.f, c6a = 0.f, c7a = 0.f;
        float d0a = 0.f, d1a = 0.f, d2a = 0.f, d3a = 0.f;
        float d4a = 0.f, d5a = 0.f, d6a = 0.f, d7a = 0.f;
#pragma unroll
        for (int k0 = 0; k0 < 64; k0 += 4) {
            float4 za = *(const float4*)(zbytes + rA + ((k0 * 4) ^ sw));
            float4 zb = *(const float4*)(zbytes + rB + ((k0 * 4) ^ sw));
            float4 zc = *(const float4*)(zbytes + rC + ((k0 * 4) ^ sw));
            float4 zd = *(const float4*)(zbytes + rD + ((k0 * 4) ^ sw));
            float4 f0 = *(const float4*)(ebase_w + 0 * 256 + k0 * 4);  // uniform
            float4 f1 = *(const float4*)(ebase_w + 1 * 256 + k0 * 4);
            float4 f2 = *(const float4*)(ebase_w + 2 * 256 + k0 * 4);
            float4 f3 = *(const float4*)(ebase_w + 3 * 256 + k0 * 4);
            float4 f4 = *(const float4*)(ebase_w + 4 * 256 + k0 * 4);
            float4 f5 = *(const float4*)(ebase_w + 5 * 256 + k0 * 4);
            float4 f6 = *(const float4*)(ebase_w + 6 * 256 + k0 * 4);
            float4 f7 = *(const float4*)(ebase_w + 7 * 256 + k0 * 4);
            a0 = fmaf(za.x, f0.x, a0); a0 = fmaf(za.y, f0.y, a0);
            a0 = fmaf(za.z, f0.z, a0); a0 = fmaf(za.w, f0.w, a0);
            a1 = fmaf(za.x, f1.x, a1); a1 = fmaf(za.y, f1.y, a1);
            a1 = fmaf(za.z, f1.z, a1); a1 = fmaf(za.w, f1.w, a1);
            a2 = fmaf(za.x, f2.x, a2); a2 = fmaf(za.y, f2.y, a2);
            a2 = fmaf(za.z, f2.z, a2); a2 = fmaf(za.w, f2.w, a2);
            a3 = fmaf(za.x, f3.x, a3); a3 = fmaf(za.y, f3.y, a3);
            a3 = fmaf(za.z, f3.z, a3); a3 = fmaf(za.w, f3.w, a3);
            a4 = fmaf(za.x, f4.x, a4); a4 = fmaf(za.y, f4.y, a4);
            a4 = fmaf(za.z, f4.z, a4); a4 = fmaf(za.w, f4.w, a4);
            a5 = fmaf(za.x, f5.x, a5); a5 = fmaf(za.y, f5.y, a5);
            a5 = fmaf(za.z, f5.z, a5); a5 = fmaf(za.w, f5.w, a5);
            a6 = fmaf(za.x, f6.x, a6); a6 = fmaf(za.y, f6.y, a6);
            a6 = fmaf(za.z, f6.z, a6); a6 = fmaf(za.w, f6.w, a6);
            a7 = fmaf(za.x, f7.x, a7); a7 = fmaf(za.y, f7.y, a7);
            a7 = fmaf(za.z, f7.z, a7); a7 = fmaf(za.w, f7.w, a7);
            b0 = fmaf(zb.x, f0.x, b0); b0 = fmaf(zb.y, f0.y, b0);
            b0 = fmaf(zb.z, f0.z, b0); b0 = fmaf(zb.w, f0.w, b0);
            b1 = fmaf(zb.x, f1.x, b1); b1 = fmaf(zb.y, f1.y, b1);
            b1 = fmaf(zb.z, f1.z, b1); b1 = fmaf(zb.w, f1.w, b1);
            b2 = fmaf(zb.x, f2.x, b2); b2 = fmaf(zb.y, f2.y, b2);
            b2 = fmaf(zb.z, f2.z, b2); b2 = fmaf(zb.w, f2.w, b2);
            b3 = fmaf(zb.x, f3.x, b3); b3 = fmaf(zb.y, f3.y, b3);
            b3 = fmaf(zb.z, f3.z, b3); b3 = fmaf(zb.w, f3.w, b3);
            b4 = fmaf(zb.x, f4.x, b4); b4 = fmaf(zb.y, f4.y, b4);
            b4 = fmaf(zb.z, f4.z, b4); b4 = fmaf(zb.w, f4.w, b4);
            b5 = fmaf(zb.x, f5.x, b5); b5 = fmaf(zb.y, f5.y, b5);
            b5 = fmaf(zb.z, f5.z, b5); b5 = fmaf(zb.w, f5.w, b5);
            b6 = fmaf(zb.x, f6.x, b6); b6 = fmaf(zb.y, f6.y, b6);
            b6 = fmaf(zb.z, f6.z, b6); b6 = fmaf(zb.w, f6.w, b6);
            b7 = fmaf(zb.x, f7.x, b7); b7 = fmaf(zb.y, f7.y, b7);
            b7 = fmaf(zb.z, f7.z, b7); b7 = fmaf(zb.w, f7.w, b7);
            c0a = fmaf(zc.x, f0.x, c0a); c0a = fmaf(zc.y, f0.y, c0a);
            c0a = fmaf(zc.z, f0.z, c0a); c0a = fmaf(zc.w, f0.w, c0a);
            c1a = fmaf(zc.x, f1.x, c1a); c1a = fmaf(zc.y, f1.y, c1a);
            c1a = fmaf(zc.z, f1.z, c1a); c1a = fmaf(zc.w, f1.w, c1a);
            c2a = fmaf(zc.x, f2.x, c2a); c2a = fmaf(zc.y, f2.y, c2a);
            c2a = fmaf(zc.z, f2.z, c2a); c2a = fmaf(zc.w, f2.w, c2a);
            c3a = fmaf(zc.x, f3.x, c3a); c3a = fmaf(zc.y, f3.y, c3a);
            c3a = fmaf(zc.z, f3.z, c3a); c3a = fmaf(zc.w, f3.w, c3a);
            c4a = fmaf(zc.x, f4.x, c4a); c4a = fmaf(zc.y, f4.y, c4a);
            c4a = fmaf(zc.z, f4.z, c4a); c4a = fmaf(zc.w, f4.w, c4a);
            c5a = fmaf(zc.x, f5.x, c5a); c5a = fmaf(zc.y, f5.y, c5a);
            c5a = fmaf(zc.z, f5.z, c5a); c5a = fmaf(zc.w, f5.w, c5a);
            c6a = fmaf(zc.x, f6.x, c6a); c6a = fmaf(zc.y, f6.y, c6a);
            c6a = fmaf(zc.z, f6.z, c6a); c6a = fmaf(zc.w, f6.w, c6a);
            c7a = fmaf(zc.x, f7.x, c7a); c7a = fmaf(zc.y, f7.y, c7a);
            c7a = fmaf(zc.z, f7.z, c7a); c7a = fmaf(zc.w, f7.w, c7a);
            d0a = fmaf(zd.x, f0.x, d0a); d0a = fmaf(zd.y, f0.y, d0a);
            d0a = fmaf(zd.z, f0.z, d0a); d0a = fmaf(zd.w, f0.w, d0a);
            d1a = fmaf(zd.x, f1.x, d1a); d1a = fmaf(zd.y, f1.y, d1a);
            d1a = fmaf(zd.z, f1.z, d1a); d1a = fmaf(zd.w, f1.w, d1a);
            d2a = fmaf(zd.x, f2.x, d2a); d2a = fmaf(zd.y, f2.y, d2a);
            d2a = fmaf(zd.z, f2.z, d2a); d2a = fmaf(zd.w, f2.w, d2a);
            d3a = fmaf(zd.x, f3.x, d3a); d3a = fmaf(zd.y, f3.y, d3a);
            d3a = fmaf(zd.z, f3.z, d3a); d3a = fmaf(zd.w, f3.w, d3a);
            d4a = fmaf(zd.x, f4.x, d4a); d4a = fmaf(zd.y, f4.y, d4a);
            d4a = fmaf(zd.z, f4.z, d4a); d4a = fmaf(zd.w, f4.w, d4a);
            d5a = fmaf(zd.x, f5.x, d5a); d5a = fmaf(zd.y, f5.y, d5a);
            d5a = fmaf(zd.z, f5.z, d5a); d5a = fmaf(zd.w, f5.w, d5a);
            d6a = fmaf(zd.x, f6.x, d6a); d6a = fmaf(zd.y, f6.y, d6a);
            d6a = fmaf(zd.z, f6.z, d6a); d6a = fmaf(zd.w, f6.w, d6a);
            d7a = fmaf(zd.x, f7.x, d7a); d7a = fmaf(zd.y, f7.y, d7a);
            d7a = fmaf(zd.z, f7.z, d7a); d7a = fmaf(zd.w, f7.w, d7a);
        }
#pragma unroll
        for (int j = 0; j < 8; ++j) {
            float aj = (j==0?a0:j==1?a1:j==2?a2:j==3?a3:j==4?a4:j==5?a5:j==6?a6:a7);
            float bj = (j==0?b0:j==1?b1:j==2?b2:j==3?b3:j==4?b4:j==5?b5:j==6?b6:b7);
            float cj = (j==0?c0a:j==1?c1a:j==2?c2a:j==3?c3a:j==4?c4a:j==5?c5a:j==6?c6a:c7a);
            float dj = (j==0?d0a:j==1?d1a:j==2?d2a:j==3?d3a:j==4?d4a:j==5?d5a:j==6?d6a:d7a);
            float es = esl[c0 + j];
            float dA = fmaf(aj, -2.0f, zsA + es);
            float dB = fmaf(bj, -2.0f, zsB + es);
            float dC = fmaf(cj, -2.0f, zsC + es);
            float dD = fmaf(dj, -2.0f, zsD + es);
            if (dA < bestA) { bestA = dA; biA = c0 + j; }
            if (dB < bestB) { bestB = dB; biB = c0 + j; }
            if (dC < bestC) { bestC = dC; biC = c0 + j; }
            if (dD < bestD) { bestD = dD; biD = c0 + j; }
        }
    }

    // Cross-wave merge: reuse the z LDS region (all z/e reads done).
    __syncthreads();
    float* sbf = zl;                  // [8][256] floats
    int*   sif = (int*)(zl + 2048);   // [8][256] ints
    sbf[wid * 256 + lane]       = bestA;  sif[wid * 256 + lane]       = biA;
    sbf[wid * 256 + lane + 64]  = bestB;  sif[wid * 256 + lane + 64]  = biB;
    sbf[wid * 256 + lane + 128] = bestC;  sif[wid * 256 + lane + 128] = biC;
    sbf[wid * 256 + lane + 192] = bestD;  sif[wid * 256 + lane + 192] = biD;
    __syncthreads();

    if (t < 256) {
        float b = sbf[t];
        int   i = sif[t];
#pragma unroll
        for (int w = 1; w < 8; ++w) {
            float ob = sbf[w * 256 + t];
            int   oi = sif[w * 256 + t];
            if (ob < b || (ob == b && oi < i)) { b = ob; i = oi; }
        }
        idx_out[blockIdx.x * 256 + t] = (float)i;
    }
}

// ---------------------------------------------------------------------------
// Kernel C: z_q_st + per-block f64 loss partials (unchanged).
// ---------------------------------------------------------------------------
__global__ __launch_bounds__(256) void output_kernel(const float* __restrict__ z,
                                                     const float* __restrict__ emb,
                                                     const float* __restrict__ idx_f,
                                                     float* __restrict__ zq_out,
                                                     double* __restrict__ partials) {
    int gid = blockIdx.x * 256 + threadIdx.x;
    int l = gid >> 6;
    int k = gid & 63;
    int idx = (int)idx_f[l];

    float zv = z[gid];
    float ev = emb[(idx << 6) + k];
    float t    = ev - zv;
    float outv = zv + t;
    zq_out[gid] = outv;

    float sq = t * t;

    __shared__ double red[256];
    red[threadIdx.x] = (double)sq;
    __syncthreads();
    for (int s = 128; s > 0; s >>= 1) {
        if (threadIdx.x < s) red[threadIdx.x] += red[threadIdx.x + s];
        __syncthreads();
    }
    if (threadIdx.x == 0) partials[blockIdx.x] = red[0];
}

// ---------------------------------------------------------------------------
// Kernel D: final deterministic reduction (unchanged).
// ---------------------------------------------------------------------------
__global__ __launch_bounds__(256) void loss_kernel(const double* __restrict__ partials,
                                                   float* __restrict__ loss_out) {
    __shared__ double red[256];
    int t = threadIdx.x;
    double s = 0.0;
    for (int i = 0; i < 64; ++i) s += partials[t * 64 + i];
    red[t] = s;
    __syncthreads();
    for (int st = 128; st > 0; st >>= 1) {
        if (t < st) red[t] += red[t + st];
        __syncthreads();
    }
    if (t == 0) {
        double m  = red[0] / (double)(L_TOK * DIM);
        float  mf = (float)m;
        loss_out[0] = 0.25f * mf + mf;
    }
}

extern "C" void kernel_launch(void* const* d_in, const int* in_sizes, int n_in,
                              void* d_out, int out_size, void* d_ws, size_t ws_size,
                              hipStream_t stream) {
    const float* z   = (const float*)d_in[0];
    const float* emb = (const float*)d_in[1];

    float* out   = (float*)d_out;
    float* zq    = out;                 // [0, 4194304)
    float* loss  = out + 4194304;       // [4194304]
    float* idxf  = out + 4194305;       // [4194305, 4259841)

    char* ws = (char*)d_ws;
    float*  esum     = (float*)ws;                      // 4 KB
    double* partials = (double*)(ws + 8192);            // 128 KB

    esum_kernel  <<<4,     256, 0, stream>>>(emb, esum);
    argmin_kernel<<<256,   512, 0, stream>>>(z, emb, esum, idxf);
    output_kernel<<<16384, 256, 0, stream>>>(z, emb, idxf, zq, partials);
    loss_kernel  <<<1,     256, 0, stream>>>(partials, loss);
}